// Round 8
// baseline (432.265 us; speedup 1.0000x reference)
//
#include <hip/hip_runtime.h>
#include <hip/hip_bf16.h>
#include <math.h>

#define CCH 256      // channels
#define MT  64       // points per block
#define ROWE 264     // padded LDS row (bf16): 528 B stride = 132 dwords = 4 mod 32 banks
#define TPB 512

typedef __attribute__((ext_vector_type(8))) short short8;
typedef __attribute__((ext_vector_type(4))) short short4v;
typedef __attribute__((ext_vector_type(4))) float f32x4;

// Pin all 16 weight fragments in VGPRs: each becomes an output of an opaque
// asm, so the compiler cannot rematerialize (re-issue) the loads afterwards.
#define PIN_W(w)                                                        \
  asm volatile(""                                                       \
               : "+v"((w)[0][0]), "+v"((w)[0][1]), "+v"((w)[0][2]),     \
                 "+v"((w)[0][3]), "+v"((w)[0][4]), "+v"((w)[0][5]),     \
                 "+v"((w)[0][6]), "+v"((w)[0][7]), "+v"((w)[1][0]),     \
                 "+v"((w)[1][1]), "+v"((w)[1][2]), "+v"((w)[1][3]),     \
                 "+v"((w)[1][4]), "+v"((w)[1][5]), "+v"((w)[1][6]),     \
                 "+v"((w)[1][7]))

__device__ __forceinline__ unsigned short f2bf(float f) {
  unsigned u = __float_as_uint(f);
  u += 0x7fffu + ((u >> 16) & 1u);   // RNE; inputs finite
  return (unsigned short)(u >> 16);
}

// Transpose + bf16-convert the two 256x256 hidden weights: T[n*256+k] = bf16(W[k*256+n])
__global__ void transpose_w(const float* __restrict__ W0,
                            const float* __restrict__ W1,
                            unsigned short* __restrict__ T0,
                            unsigned short* __restrict__ T1) {
  __shared__ float tile[32][33];
  const float* src = blockIdx.z ? W1 : W0;
  unsigned short* dst = blockIdx.z ? T1 : T0;
  const int tx = threadIdx.x, ty = threadIdx.y;       // 32 x 8
  const int k0 = blockIdx.y * 32, n0 = blockIdx.x * 32;
#pragma unroll
  for (int r = 0; r < 4; ++r)
    tile[ty + r * 8][tx] = src[(k0 + ty + r * 8) * CCH + n0 + tx];
  __syncthreads();
#pragma unroll
  for (int r = 0; r < 4; ++r) {
    const int n = n0 + ty + r * 8;
    dst[n * CCH + k0 + tx] = f2bf(tile[tx][ty + r * 8]);
  }
}

// Wo_t[16][256] bf16, zero-padded: Wo_t[j][k] = W_out[k*3+j] for j<3 else 0
__global__ void prep_wo(const float* __restrict__ W_out,
                        unsigned short* __restrict__ Wo_t) {
  const int k = threadIdx.x;   // 256 threads
#pragma unroll
  for (int j = 0; j < 16; ++j)
    Wo_t[j * CCH + k] = (j < 3) ? f2bf(W_out[k * 3 + j]) : (unsigned short)0;
}

// Prefetch one layer's weight fragments for this wave's 32 output channels.
template <bool TR>
__device__ __forceinline__ void load_w(short8 w[2][8],
                                       const unsigned short* __restrict__ Wt,
                                       const float* __restrict__ Wraw,
                                       int wv, int l16, int lk8) {
#pragma unroll
  for (int kk = 0; kk < 8; ++kk) {
    const int k = kk * 32 + lk8 * 8;
    if constexpr (TR) {
      w[0][kk] = *(const short8*)&Wt[(wv * 32 + l16) * CCH + k];
      w[1][kk] = *(const short8*)&Wt[(wv * 32 + 16 + l16) * CCH + k];
    } else {
      const int n = wv * 32 + l16;
#pragma unroll
      for (int j = 0; j < 8; ++j) {
        w[0][kk][j] = (short)f2bf(Wraw[(k + j) * CCH + n]);
        w[1][kk][j] = (short)f2bf(Wraw[(k + j) * CCH + n + 16]);
      }
    }
  }
}

// MFMA main loop (SWAPPED operands: D = W^T * h^T)
__device__ __forceinline__ void mfma_loop(
    const unsigned short (*__restrict__ src)[ROWE],
    const short8 w[2][8], f32x4 acc[4][2], int l16, int lk8) {
#pragma unroll
  for (int mt = 0; mt < 4; ++mt)
#pragma unroll
    for (int nt = 0; nt < 2; ++nt)
      acc[mt][nt] = (f32x4){0.f, 0.f, 0.f, 0.f};

#pragma unroll
  for (int kk = 0; kk < 8; ++kk) {
    const int k = kk * 32 + lk8 * 8;
#pragma unroll
    for (int mt = 0; mt < 4; ++mt) {
      const short8 a = *(const short8*)&src[mt * 16 + l16][k];
      acc[mt][0] = __builtin_amdgcn_mfma_f32_16x16x32_bf16(w[0][kk], a, acc[mt][0], 0, 0, 0);
      acc[mt][1] = __builtin_amdgcn_mfma_f32_16x16x32_bf16(w[1][kk], a, acc[mt][1], 0, 0, 0);
    }
  }
}

// bias + relu + bf16 pack; lane holds 4 consecutive channels of one point
__device__ __forceinline__ void epilogue_store(
    const f32x4 acc[4][2], unsigned short (*__restrict__ dst)[ROWE],
    const float* __restrict__ bias, int wv, int l16, int lk8) {
#pragma unroll
  for (int nt = 0; nt < 2; ++nt) {
    const int ch0 = wv * 32 + nt * 16 + lk8 * 4;
    const f32x4 bv = *(const f32x4*)&bias[ch0];
#pragma unroll
    for (int mt = 0; mt < 4; ++mt) {
      const int pt = mt * 16 + l16;
      short4v pk;
#pragma unroll
      for (int i = 0; i < 4; ++i)
        pk[i] = (short)f2bf(fmaxf(acc[mt][nt][i] + bv[i], 0.0f));
      *(short4v*)&dst[pt][ch0] = pk;   // 8B aligned
    }
  }
}

template <bool TR>
__global__ __launch_bounds__(TPB, 4) void nerf_fused(
    const float* __restrict__ uv,
    const float* __restrict__ W_in, const float* __restrict__ b_in,
    const float* __restrict__ W_h0r, const float* __restrict__ b_h0,
    const float* __restrict__ W_h1r, const float* __restrict__ b_h1,
    const float* __restrict__ W_out, const float* __restrict__ b_out,
    const unsigned short* __restrict__ T0,
    const unsigned short* __restrict__ T1,
    const unsigned short* __restrict__ Wo_t,
    float* __restrict__ out) {
  __shared__ unsigned short hA[MT][ROWE];
  __shared__ unsigned short hB[MT][ROWE];

  const int tid = threadIdx.x;
  const long n0 = (long)blockIdx.x * MT;
  const int wv = tid >> 6, ln = tid & 63;
  const int l16 = ln & 15, lk8 = ln >> 4;

  // issue gemm0 weight prefetch FIRST; layer 0's VALU work hides L2 latency
  short8 w[2][8];
  load_w<TR>(w, T0, W_h0r, wv, l16, lk8);

  { // ---- layer 0: enc=[cos u, cos v, sin u, sin v] -> relu(enc@W_in+b_in)
    const int p = tid >> 3;
    const int t7 = tid & 7;
    const float u = uv[(n0 + p) * 2 + 0];
    const float v = uv[(n0 + p) * 2 + 1];
    const float e0 = __cosf(u), e1 = __cosf(v), e2 = __sinf(u), e3 = __sinf(v);
#pragma unroll
    for (int j = 0; j < 8; ++j) {
      const int c = t7 * 4 + j * 32;
      const f32x4 w0 = *(const f32x4*)&W_in[0 * CCH + c];
      const f32x4 w1 = *(const f32x4*)&W_in[1 * CCH + c];
      const f32x4 w2 = *(const f32x4*)&W_in[2 * CCH + c];
      const f32x4 w3 = *(const f32x4*)&W_in[3 * CCH + c];
      const f32x4 bb = *(const f32x4*)&b_in[c];
      short4v pk;
#pragma unroll
      for (int i = 0; i < 4; ++i) {
        const float x = bb[i] + e0 * w0[i] + e1 * w1[i] + e2 * w2[i] + e3 * w3[i];
        pk[i] = (short)f2bf(fmaxf(x, 0.0f));
      }
      *(short4v*)&hA[p][c] = pk;
    }
  }
  PIN_W(w);          // materialize T0 fragments in VGPRs; no remat past here
  __syncthreads();

  f32x4 acc[4][2];
  mfma_loop(hA, w, acc, l16, lk8);                // gemm0 MFMAs (consume w)
  load_w<TR>(w, T1, W_h1r, wv, l16, lk8);         // refill; epilogue hides latency
  epilogue_store(acc, hB, b_h0, wv, l16, lk8);
  PIN_W(w);          // materialize T1 fragments
  __syncthreads();

  mfma_loop(hB, w, acc, l16, lk8);                // gemm1
  epilogue_store(acc, hA, b_h1, wv, l16, lk8);
  __syncthreads();

  // ---- output layer via MFMA: D = Wo(3x256,zero-pad to 16) @ h2^T ----
  if (wv < 4) {                                   // wave wv owns points wv*16..+15
    f32x4 oacc = (f32x4){0.f, 0.f, 0.f, 0.f};
#pragma unroll
    for (int kk = 0; kk < 8; ++kk) {
      const int k = kk * 32 + lk8 * 8;
      short8 wo;
      if constexpr (TR) {
        wo = *(const short8*)&Wo_t[l16 * CCH + k];
      } else {
#pragma unroll
        for (int j = 0; j < 8; ++j)
          wo[j] = (l16 < 3) ? (short)f2bf(W_out[(k + j) * 3 + l16]) : (short)0;
      }
      const short8 hb = *(const short8*)&hA[wv * 16 + l16][k];
      oacc = __builtin_amdgcn_mfma_f32_16x16x32_bf16(wo, hb, oacc, 0, 0, 0);
    }
    // D: col=l16=point, row=lk8*4+i=output j; only lk8==0, j<3 are real
    if (lk8 == 0) {
      const long pt = n0 + wv * 16 + l16;
#pragma unroll
      for (int i = 0; i < 3; ++i)
        out[pt * 3 + i] = 1.f / (1.f + __expf(-(oacc[i] + b_out[i])));
    }
  }
}

extern "C" void kernel_launch(void* const* d_in, const int* in_sizes, int n_in,
                              void* d_out, int out_size, void* d_ws, size_t ws_size,
                              hipStream_t stream) {
  const float* uv    = (const float*)d_in[0];
  const float* W_in  = (const float*)d_in[1];
  const float* b_in  = (const float*)d_in[2];
  const float* W_h0  = (const float*)d_in[3];
  const float* b_h0  = (const float*)d_in[4];
  const float* W_h1  = (const float*)d_in[5];
  const float* b_h1  = (const float*)d_in[6];
  const float* W_out = (const float*)d_in[7];
  const float* b_out = (const float*)d_in[8];

  const int N = in_sizes[0] / 2;                    // 524288
  const size_t t_bytes =
      (size_t)(2 * CCH * CCH + 16 * CCH) * sizeof(unsigned short);  // 264 KiB

  if (ws_size >= t_bytes) {
    unsigned short* T0 = (unsigned short*)d_ws;     // 256*256 bf16
    unsigned short* T1 = T0 + CCH * CCH;
    unsigned short* Wo = T1 + CCH * CCH;            // 16*256 bf16
    transpose_w<<<dim3(8, 8, 2), dim3(32, 8), 0, stream>>>(W_h0, W_h1, T0, T1);
    prep_wo<<<1, CCH, 0, stream>>>(W_out, Wo);
    nerf_fused<true><<<dim3(N / MT), dim3(TPB), 0, stream>>>(
        uv, W_in, b_in, W_h0, b_h0, W_h1, b_h1, W_out, b_out, T0, T1, Wo,
        (float*)d_out);
  } else {
    nerf_fused<false><<<dim3(N / MT), dim3(TPB), 0, stream>>>(
        uv, W_in, b_in, W_h0, b_h0, W_h1, b_h1, W_out, b_out,
        (const unsigned short*)nullptr, (const unsigned short*)nullptr,
        (const unsigned short*)nullptr, (float*)d_out);
  }
}

// Round 9
// 418.726 us; speedup vs baseline: 1.0323x; 1.0323x over previous
//
#include <hip/hip_runtime.h>
#include <hip/hip_bf16.h>
#include <math.h>

#define CCH 256      // channels
#define MT  64       // points per block
#define ROWE 264     // padded LDS row (bf16): 528 B stride = 132 dwords = 4 mod 32 banks
#define TPB 512

typedef __attribute__((ext_vector_type(8))) short short8;
typedef __attribute__((ext_vector_type(4))) short short4v;
typedef __attribute__((ext_vector_type(4))) float f32x4;

// Module-scope device scratch: transposed bf16 weights. No d_ws dependency,
// no hipMalloc; rewritten every kernel_launch (same work each call).
__device__ unsigned short g_T0[CCH * CCH];   // T0[n*256+k] = bf16(W_h0[k][n])
__device__ unsigned short g_T1[CCH * CCH];   // T1[n*256+k] = bf16(W_h1[k][n])
__device__ unsigned short g_Wo[16 * CCH];    // Wo[j][k] = bf16(W_out[k][j]), j<3 else 0

__device__ __forceinline__ unsigned short f2bf(float f) {
  unsigned u = __float_as_uint(f);
  u += 0x7fffu + ((u >> 16) & 1u);   // RNE; inputs finite
  return (unsigned short)(u >> 16);
}

// Transpose + bf16-convert the two 256x256 hidden weights.
__global__ void transpose_w(const float* __restrict__ W0,
                            const float* __restrict__ W1) {
  __shared__ float tile[32][33];
  const float* src = blockIdx.z ? W1 : W0;
  unsigned short* dst = blockIdx.z ? g_T1 : g_T0;
  const int tx = threadIdx.x, ty = threadIdx.y;       // 32 x 8
  const int k0 = blockIdx.y * 32, n0 = blockIdx.x * 32;
#pragma unroll
  for (int r = 0; r < 4; ++r)
    tile[ty + r * 8][tx] = src[(k0 + ty + r * 8) * CCH + n0 + tx];
  __syncthreads();
#pragma unroll
  for (int r = 0; r < 4; ++r) {
    const int n = n0 + ty + r * 8;
    dst[n * CCH + k0 + tx] = f2bf(tile[tx][ty + r * 8]);
  }
}

__global__ void prep_wo(const float* __restrict__ W_out) {
  const int k = threadIdx.x;   // 256 threads
#pragma unroll
  for (int j = 0; j < 16; ++j)
    g_Wo[j * CCH + k] = (j < 3) ? f2bf(W_out[k * 3 + j]) : (unsigned short)0;
}

// Prefetch one layer's weight fragments for this wave's 32 output channels.
__device__ __forceinline__ void load_w(short8 w[2][8],
                                       const unsigned short* __restrict__ Wt,
                                       int wv, int l16, int lk8) {
#pragma unroll
  for (int kk = 0; kk < 8; ++kk) {
    const int k = kk * 32 + lk8 * 8;
    w[0][kk] = *(const short8*)&Wt[(wv * 32 + l16) * CCH + k];
    w[1][kk] = *(const short8*)&Wt[(wv * 32 + 16 + l16) * CCH + k];
  }
}

// dst = relu(src @ W + b), SWAPPED mfma operands (D = W^T * h^T): lane holds
// 4 consecutive channels of one point -> aligned b64 LDS writes.
__device__ __forceinline__ void layer_mfma(
    const unsigned short (*__restrict__ src)[ROWE],
    unsigned short (*__restrict__ dst)[ROWE],
    const short8 w[2][8],
    const float* __restrict__ bias,
    int wv, int l16, int lk8) {
  f32x4 acc[4][2];
#pragma unroll
  for (int mt = 0; mt < 4; ++mt)
#pragma unroll
    for (int nt = 0; nt < 2; ++nt)
      acc[mt][nt] = (f32x4){0.f, 0.f, 0.f, 0.f};

#pragma unroll
  for (int kk = 0; kk < 8; ++kk) {
    const int k = kk * 32 + lk8 * 8;
#pragma unroll
    for (int mt = 0; mt < 4; ++mt) {
      const short8 a = *(const short8*)&src[mt * 16 + l16][k];
      acc[mt][0] = __builtin_amdgcn_mfma_f32_16x16x32_bf16(w[0][kk], a, acc[mt][0], 0, 0, 0);
      acc[mt][1] = __builtin_amdgcn_mfma_f32_16x16x32_bf16(w[1][kk], a, acc[mt][1], 0, 0, 0);
    }
  }

  // D[ch][pt]: pt = mt*16 + l16, ch = wv*32 + nt*16 + lk8*4 + i
#pragma unroll
  for (int nt = 0; nt < 2; ++nt) {
    const int ch0 = wv * 32 + nt * 16 + lk8 * 4;
    const f32x4 bv = *(const f32x4*)&bias[ch0];
#pragma unroll
    for (int mt = 0; mt < 4; ++mt) {
      const int pt = mt * 16 + l16;
      short4v pk;
#pragma unroll
      for (int i = 0; i < 4; ++i)
        pk[i] = (short)f2bf(fmaxf(acc[mt][nt][i] + bv[i], 0.0f));
      *(short4v*)&dst[pt][ch0] = pk;   // 8B aligned
    }
  }
}

__global__ __launch_bounds__(TPB, 4) void nerf_fused(
    const float* __restrict__ uv,
    const float* __restrict__ W_in, const float* __restrict__ b_in,
    const float* __restrict__ b_h0, const float* __restrict__ b_h1,
    const float* __restrict__ b_out,
    float* __restrict__ out) {
  __shared__ unsigned short hA[MT][ROWE];
  __shared__ unsigned short hB[MT][ROWE];

  const int tid = threadIdx.x;
  const long n0 = (long)blockIdx.x * MT;
  const int wv = tid >> 6, ln = tid & 63;
  const int l16 = ln & 15, lk8 = ln >> 4;

  // issue gemm0 weight prefetch FIRST; layer 0's VALU work hides L2 latency
  short8 w[2][8];
  load_w(w, g_T0, wv, l16, lk8);
  asm volatile("" ::: "memory");

  { // ---- layer 0: enc=[cos u, cos v, sin u, sin v] -> relu(enc@W_in+b_in)
    const int p = tid >> 3;
    const int t7 = tid & 7;
    const float u = uv[(n0 + p) * 2 + 0];
    const float v = uv[(n0 + p) * 2 + 1];
    const float e0 = __cosf(u), e1 = __cosf(v), e2 = __sinf(u), e3 = __sinf(v);
#pragma unroll
    for (int j = 0; j < 8; ++j) {
      const int c = t7 * 4 + j * 32;
      const f32x4 w0 = *(const f32x4*)&W_in[0 * CCH + c];
      const f32x4 w1 = *(const f32x4*)&W_in[1 * CCH + c];
      const f32x4 w2 = *(const f32x4*)&W_in[2 * CCH + c];
      const f32x4 w3 = *(const f32x4*)&W_in[3 * CCH + c];
      const f32x4 bb = *(const f32x4*)&b_in[c];
      short4v pk;
#pragma unroll
      for (int i = 0; i < 4; ++i) {
        const float x = bb[i] + e0 * w0[i] + e1 * w1[i] + e2 * w2[i] + e3 * w3[i];
        pk[i] = (short)f2bf(fmaxf(x, 0.0f));
      }
      *(short4v*)&hA[p][c] = pk;
    }
  }
  __syncthreads();

  layer_mfma(hA, hB, w, b_h0, wv, l16, lk8);      // h0 -> h1 (consumes w)
  load_w(w, g_T1, wv, l16, lk8);                  // refill; in flight over sync
  asm volatile("" ::: "memory");
  __syncthreads();
  layer_mfma(hB, hA, w, b_h1, wv, l16, lk8);      // h1 -> h2
  __syncthreads();

  // ---- output layer via MFMA: D = Wo(3x256, zero-pad to 16) @ h2^T ----
  if (wv < 4) {                                   // wave wv owns points wv*16..+15
    f32x4 oacc = (f32x4){0.f, 0.f, 0.f, 0.f};
#pragma unroll
    for (int kk = 0; kk < 8; ++kk) {
      const int k = kk * 32 + lk8 * 8;
      const short8 wo = *(const short8*)&g_Wo[l16 * CCH + k];
      const short8 hb = *(const short8*)&hA[wv * 16 + l16][k];
      oacc = __builtin_amdgcn_mfma_f32_16x16x32_bf16(wo, hb, oacc, 0, 0, 0);
    }
    // D: col=l16=point, row=lk8*4+i=output j; only lk8==0, j<3 are real
    if (lk8 == 0) {
      const long pt = n0 + wv * 16 + l16;
#pragma unroll
      for (int i = 0; i < 3; ++i)
        out[pt * 3 + i] = 1.f / (1.f + __expf(-(oacc[i] + b_out[i])));
    }
  }
}

extern "C" void kernel_launch(void* const* d_in, const int* in_sizes, int n_in,
                              void* d_out, int out_size, void* d_ws, size_t ws_size,
                              hipStream_t stream) {
  const float* uv    = (const float*)d_in[0];
  const float* W_in  = (const float*)d_in[1];
  const float* b_in  = (const float*)d_in[2];
  const float* W_h0  = (const float*)d_in[3];
  const float* b_h0  = (const float*)d_in[4];
  const float* W_h1  = (const float*)d_in[5];
  const float* b_h1  = (const float*)d_in[6];
  const float* W_out = (const float*)d_in[7];
  const float* b_out = (const float*)d_in[8];

  const int N = in_sizes[0] / 2;                    // 524288

  transpose_w<<<dim3(8, 8, 2), dim3(32, 8), 0, stream>>>(W_h0, W_h1);
  prep_wo<<<1, CCH, 0, stream>>>(W_out);
  nerf_fused<<<dim3(N / MT), dim3(TPB), 0, stream>>>(
      uv, W_in, b_in, b_h0, b_h1, b_out, (float*)d_out);
}